// Round 6
// baseline (2438.451 us; speedup 1.0000x reference)
//
#include <hip/hip_runtime.h>
#include <stdint.h>

#define NB 8
#define NPTS 4096
#define NPOINT 1024
#define NSAMPLE 32
#define FCH 64
#define HID 128
#define CAPW 160  // per-wave candidate cap (512-pt segment, expected ~7)

typedef unsigned long long ull;

// d2 computed with EXACT numpy rounding/order: ((dx*dx + dy*dy) + dz*dz),
// no FMA contraction (FPS argmax + radius selection must match ref bitwise).
__device__ __forceinline__ float d2_exact(float ax, float ay, float az,
                                          float bx, float by, float bz) {
  float dx = ax - bx, dy = ay - by, dz = az - bz;
  return __fadd_rn(__fadd_rn(__fmul_rn(dx, dx), __fmul_rn(dy, dy)),
                   __fmul_rn(dz, dz));
}

// DPP f32 max step (identity 0 valid: dists >= 0). VALU pipe.
#define DPPMAX(v, ctrl)                                                     \
  v = fmaxf(v, __int_as_float(__builtin_amdgcn_update_dpp(                  \
                 0, __float_as_int(v), ctrl, 0xf, 0xf, true)))

// ---------------- shared memory union, padded to 84KB ----------------------
// 84KB forces <=1 block/CU: with grid=256 every CU hosts exactly one block,
// so the 8 producers get DEDICATED CUs (R5 lesson: co-resident consumers
// wreck both the FPS chain and each other — LDS conflicts went 53K -> 4.2M).
struct ProdS {
  float4 pts[NPTS];     // 64 KB
  float chunk[64 * 3];  // 64-centroid publish buffer
  float4 wkd4[2];       // per-wave max dist (parity dbuf)
  int4 wki4[2];         // per-wave argmax idx
};
struct ConsS {
  float fin[32][68];  // dxyz 0..2, feats 3..66, pad 67
  float fm[HID];
  int sidx[NSAMPLE];
  int scnt[8];
  int tkS;
  union {  // knn candidates overlaid on GEMM buffers (dead during knn)
    float bufA[32][HID];    // h1 then h2 (16KB)
    ull candseg[8][CAPW];   // 10.2KB
  };
  union {
    float fp[32][HID];      // f_prime (16KB)
    ull cand2[8 * CAPW];    // 10.2KB
  };
};
union SMemU {
  ProdS p;
  ConsS c;
  unsigned char pad_[86016];  // 84KB -> 1 block/CU guaranteed
};

// ---------------------------------------------------------------- FPS
// R3/R4-proven chain, threads 0-255 active; the block has 512 threads, so
// idle waves 4-7 execute only the (uniform) barrier skeleton.
__device__ void run_fps(const float* __restrict__ xyz,
                        float* __restrict__ newxyz, int* progress, int b,
                        ProdS& S) {
  const int t = threadIdx.x;
  const int wid = t >> 6;
  const bool act = (t < 256);
  const float* src = xyz + (size_t)b * NPTS * 3;
  float* dstb = newxyz + (size_t)b * NPOINT * 3;
  for (int j = t; j < NPTS; j += 512) {
    const float* p = src + 3 * j;
    S.pts[j] = make_float4(p[0], p[1], p[2], 0.f);
  }
  __syncthreads();
  const int base = t * 16;
  float px[16], py[16], pz[16], dist[16];
  float bv = -INFINITY;
  int br = 0;
  if (act) {
    const float4 c0 = S.pts[0];
#pragma unroll
    for (int r = 0; r < 16; ++r) {
      float4 p = S.pts[base + r];
      px[r] = p.x; py[r] = p.y; pz[r] = p.z;
      dist[r] = d2_exact(px[r], py[r], pz[r], c0.x, c0.y, c0.z);
      bool c = dist[r] > bv;  // strict > keeps lowest r (idx) on ties
      bv = c ? dist[r] : bv;
      br = c ? r : br;
    }
    if (t == 0) {
      S.chunk[0] = c0.x; S.chunk[1] = c0.y; S.chunk[2] = c0.z;
    }
  }
  for (int it = 1; it < NPOINT; ++it) {
    const int par = it & 1;
    if (act) {
      float wm = bv;
      DPPMAX(wm, 0x111); DPPMAX(wm, 0x112); DPPMAX(wm, 0x114);
      DPPMAX(wm, 0x118); DPPMAX(wm, 0x142); DPPMAX(wm, 0x143);
      float gmaxw =
          __int_as_float(__builtin_amdgcn_readlane(__float_as_int(wm), 63));
      ull m = __ballot(bv == gmaxw);
      int lead = __ffsll((long long)m) - 1;  // lowest lane == lowest index
      int widx = __builtin_amdgcn_readlane(base + br, lead);
      if ((t & 63) == 0) {
        ((float*)&S.wkd4[par])[wid] = gmaxw;
        ((int*)&S.wki4[par])[wid] = widx;
      }
    }
    __syncthreads();  // parity double-buffer -> single barrier/iter
    if ((it & 63) == 0) {
      if (t < 192) {
        dstb[(it - 64) * 3 + t] = S.chunk[t];
        __threadfence();
      }
      __syncthreads();
      if (t == 0)
        __hip_atomic_store(&progress[b], it, __ATOMIC_RELEASE,
                           __HIP_MEMORY_SCOPE_AGENT);
    }
    if (act) {
      float4 dd = S.wkd4[par];
      int4 ii = S.wki4[par];
      float d = dd.x; int fi = ii.x;
      bool c1 = (dd.y > d) || (dd.y == d && ii.y < fi);
      d = c1 ? dd.y : d; fi = c1 ? ii.y : fi;
      bool c2 = (dd.z > d) || (dd.z == d && ii.z < fi);
      d = c2 ? dd.z : d; fi = c2 ? ii.z : fi;
      bool c3 = (dd.w > d) || (dd.w == d && ii.w < fi);
      fi = c3 ? ii.w : fi;
      const float4 cp = S.pts[fi];
      if (t == 0) {
        int slot = (it & 63) * 3;
        S.chunk[slot + 0] = cp.x;
        S.chunk[slot + 1] = cp.y;
        S.chunk[slot + 2] = cp.z;
      }
      bv = -INFINITY;
      br = 0;
#pragma unroll
      for (int r = 0; r < 16; ++r) {
        float dnew = d2_exact(px[r], py[r], pz[r], cp.x, cp.y, cp.z);
        float nd = fminf(dist[r], dnew);
        dist[r] = nd;
        bool c = nd > bv;
        bv = c ? nd : bv;
        br = c ? r : br;
      }
    }
  }
  __syncthreads();  // chunk holds centroids [960,1024)
  if (t < 192) {
    dstb[(NPOINT - 64) * 3 + t] = S.chunk[t];
    __threadfence();
  }
  __syncthreads();
  if (t == 0)
    __hip_atomic_store(&progress[b], NPOINT, __ATOMIC_RELEASE,
                       __HIP_MEMORY_SCOPE_AGENT);
}

// ---------------------------------------------------------------- MLP gemms
// 2-sample x 4-channel tiles (512-thread block). W streamed from global/L2
// (R1/R3-proven; LDS staging spilled in R2).
template <int K>
__device__ __forceinline__ void gemm_tile2(const float* __restrict__ a0,
                                           const float* __restrict__ a1,
                                           const float* __restrict__ W,
                                           float acc[2][4]) {
  int k = 0;
  for (; k + 4 <= K; k += 4) {
    float4 A0 = *(const float4*)(a0 + k);
    float4 A1 = *(const float4*)(a1 + k);
#pragma unroll
    for (int kk = 0; kk < 4; ++kk) {
      float4 w = *(const float4*)(W + (size_t)(k + kk) * HID);
      float e0 = (&A0.x)[kk], e1 = (&A1.x)[kk];
      acc[0][0] += e0 * w.x; acc[0][1] += e0 * w.y; acc[0][2] += e0 * w.z; acc[0][3] += e0 * w.w;
      acc[1][0] += e1 * w.x; acc[1][1] += e1 * w.y; acc[1][2] += e1 * w.z; acc[1][3] += e1 * w.w;
    }
  }
  for (; k < K; ++k) {
    float4 w = *(const float4*)(W + (size_t)k * HID);
    float e0 = a0[k], e1 = a1[k];
    acc[0][0] += e0 * w.x; acc[0][1] += e0 * w.y; acc[0][2] += e0 * w.z; acc[0][3] += e0 * w.w;
    acc[1][0] += e1 * w.x; acc[1][1] += e1 * w.y; acc[1][2] += e1 * w.z; acc[1][3] += e1 * w.w;
  }
}

__device__ __forceinline__ void gemm_tile2_corr(const float* __restrict__ a0,
                                                const float* __restrict__ a1,
                                                const float* __restrict__ W,
                                                const float* __restrict__ fm,
                                                float acc[2][4],
                                                float corr[4]) {
  for (int k = 0; k < HID; k += 4) {
    float4 A0 = *(const float4*)(a0 + k);
    float4 A1 = *(const float4*)(a1 + k);
    float4 FM = *(const float4*)(fm + k);
#pragma unroll
    for (int kk = 0; kk < 4; ++kk) {
      float4 w = *(const float4*)(W + (size_t)(k + kk) * HID);
      float e0 = (&A0.x)[kk], e1 = (&A1.x)[kk], cf = (&FM.x)[kk];
      acc[0][0] += e0 * w.x; acc[0][1] += e0 * w.y; acc[0][2] += e0 * w.z; acc[0][3] += e0 * w.w;
      acc[1][0] += e1 * w.x; acc[1][1] += e1 * w.y; acc[1][2] += e1 * w.z; acc[1][3] += e1 * w.w;
      corr[0] += cf * w.x; corr[1] += cf * w.y; corr[2] += cf * w.z; corr[3] += cf * w.w;
    }
  }
}

// ---------------------------------------------------------------- consumer
__device__ void run_consumer(const float* __restrict__ xyz,
                             const float* __restrict__ feats,
                             const float* __restrict__ W1f,
                             const float* __restrict__ b1f,
                             const float* __restrict__ W2f,
                             const float* __restrict__ b2f,
                             const float* __restrict__ W1w,
                             const float* __restrict__ b1w,
                             const float* __restrict__ W2w,
                             const float* __restrict__ b2w,
                             const float* __restrict__ newxyz,
                             float* __restrict__ fout, int* progress,
                             int* ticket, ConsS& S) {
  const int t = threadIdx.x;
  const int wv = t >> 6;   // 0..7
  const int lane = t & 63;
  const float r2 = 0.0225f;  // np float32(RADIUS**2)

  while (true) {
    if (t == 0) S.tkS = atomicAdd(ticket, 1);
    __syncthreads();
    const int tk = S.tkS;
    if (tk >= NB * NPOINT) return;
    const int it = tk >> 3;
    const int b = tk & 7;
    const int g = b * NPOINT + it;

    // wait until centroid `it` of batch b is published
    if (t == 0) {
      while (__hip_atomic_load(&progress[b], __ATOMIC_RELAXED,
                               __HIP_MEMORY_SCOPE_AGENT) <= it)
        __builtin_amdgcn_s_sleep(32);
    }
    __syncthreads();
    {  // every thread acquires (orders its own subsequent loads)
      int pv = __hip_atomic_load(&progress[b], __ATOMIC_ACQUIRE,
                                 __HIP_MEMORY_SCOPE_AGENT);
      while (pv <= it) {
        __builtin_amdgcn_s_sleep(8);
        pv = __hip_atomic_load(&progress[b], __ATOMIC_ACQUIRE,
                               __HIP_MEMORY_SCOPE_AGENT);
      }
    }
    const float cx = newxyz[g * 3 + 0];
    const float cy = newxyz[g * 3 + 1];
    const float cz = newxyz[g * 3 + 2];

    // ---- knn: 8-wave scan (512 pts each), compaction, rank-select 32
    const float* src = xyz + (size_t)b * NPTS * 3;
    int cnt = 0;
    const int jb = wv * 512;
    for (int j0 = jb; j0 < jb + 512; j0 += 64) {
      const int p = j0 + lane;
      const float* pp = src + p * 3;
      float d2 = d2_exact(pp[0], pp[1], pp[2], cx, cy, cz);
      bool inr = (d2 <= r2);
      ull mask = __ballot(inr);
      if (inr) {
        int pos = cnt + __popcll(mask & ((1ull << lane) - 1ull));
        if (pos < CAPW)
          S.candseg[wv][pos] = ((ull)__float_as_uint(d2) << 32) | (unsigned)p;
      }
      cnt += __popcll(mask);
    }
    if (lane == 0) S.scnt[wv] = cnt < CAPW ? cnt : CAPW;
    __syncthreads();
    int C = 0, off = 0;
#pragma unroll
    for (int w = 0; w < 8; ++w) {
      int n = S.scnt[w];
      if (w < wv) off += n;
      C += n;
    }
    {
      int myn = S.scnt[wv];
      for (int i = lane; i < myn; i += 64) S.cand2[off + i] = S.candseg[wv][i];
    }
    __syncthreads();
    for (int tt = t; tt < C; tt += 512) {
      ull key = S.cand2[tt];
      int rank = 0;
      for (int u = 0; u < C; ++u) rank += (S.cand2[u] < key) ? 1 : 0;
      if (rank < NSAMPLE) S.sidx[rank] = (int)(key & 0xffffffffu);
    }
    if (C < NSAMPLE && wv == 0) {  // boundary fill: lowest-index outside pts
      const float* pp = src + lane * 3;
      float d2 = d2_exact(pp[0], pp[1], pp[2], cx, cy, cz);
      bool outr = !(d2 <= r2);
      ull mask = __ballot(outr);
      if (outr) {
        int pos = __popcll(mask & ((1ull << lane) - 1ull));
        if (pos < NSAMPLE - C) S.sidx[C + pos] = lane;
      }
    }
    __syncthreads();

    // ---- mlp (R3-proven structure, 2x4 tiles)
    if (t < 32) {
      const float* pp = src + (size_t)S.sidx[t] * 3;
      S.fin[t][0] = pp[0] - cx;
      S.fin[t][1] = pp[1] - cy;
      S.fin[t][2] = pp[2] - cz;
      S.fin[t][67] = 0.f;
    }
    for (int e = t; e < 32 * FCH; e += 512) {
      int s = e >> 6;
      int c = e & 63;
      S.fin[s][3 + c] = feats[((size_t)b * NPTS + S.sidx[s]) * FCH + c];
    }
    __syncthreads();

    const int s0 = (t >> 5) * 2;   // 16 groups x 2 samples
    const int c0 = (t & 31) * 4;   // 32 groups x 4 channels
    float acc[2][4];

    // G1
    {
      float4 bv4 = *(const float4*)(b1f + c0);
#pragma unroll
      for (int i = 0; i < 2; ++i) { acc[i][0] = bv4.x; acc[i][1] = bv4.y; acc[i][2] = bv4.z; acc[i][3] = bv4.w; }
    }
    gemm_tile2<67>(S.fin[s0], S.fin[s0 + 1], W1f + c0, acc);
#pragma unroll
    for (int i = 0; i < 2; ++i)
#pragma unroll
      for (int j = 0; j < 4; ++j) S.bufA[s0 + i][c0 + j] = fmaxf(acc[i][j], 0.f);
    __syncthreads();

    // G2
    {
      float4 bv4 = *(const float4*)(b2f + c0);
#pragma unroll
      for (int i = 0; i < 2; ++i) { acc[i][0] = bv4.x; acc[i][1] = bv4.y; acc[i][2] = bv4.z; acc[i][3] = bv4.w; }
    }
    gemm_tile2<128>(S.bufA[s0], S.bufA[s0 + 1], W2f + c0, acc);
#pragma unroll
    for (int i = 0; i < 2; ++i)
#pragma unroll
      for (int j = 0; j < 4; ++j) S.fp[s0 + i][c0 + j] = fmaxf(acc[i][j], 0.f);
    __syncthreads();

    if (t < HID) {
      float s = 0.f;
#pragma unroll 8
      for (int i = 0; i < 32; ++i) s += S.fp[i][t];
      S.fm[t] = s * (1.0f / 32.0f);
    }
    __syncthreads();

    // G3: relu( fp@W1w[3:] + (b1w + dxyz@W1w[0:3]) - fm@W1w[3:] )
    float corr[4] = {0.f, 0.f, 0.f, 0.f};
    {
      float4 bv4 = *(const float4*)(b1w + c0);
      float4 w0 = *(const float4*)(W1w + 0 * HID + c0);
      float4 w1 = *(const float4*)(W1w + 1 * HID + c0);
      float4 w2 = *(const float4*)(W1w + 2 * HID + c0);
#pragma unroll
      for (int i = 0; i < 2; ++i) {
        float dx = S.fin[s0 + i][0], dy = S.fin[s0 + i][1], dz = S.fin[s0 + i][2];
        acc[i][0] = bv4.x + dx * w0.x + dy * w1.x + dz * w2.x;
        acc[i][1] = bv4.y + dx * w0.y + dy * w1.y + dz * w2.y;
        acc[i][2] = bv4.z + dx * w0.z + dy * w1.z + dz * w2.z;
        acc[i][3] = bv4.w + dx * w0.w + dy * w1.w + dz * w2.w;
      }
    }
    gemm_tile2_corr(S.fp[s0], S.fp[s0 + 1], W1w + 3 * HID + c0, S.fm, acc,
                    corr);
    __syncthreads();  // h1 reads done before bufA overwrite
#pragma unroll
    for (int i = 0; i < 2; ++i)
#pragma unroll
      for (int j = 0; j < 4; ++j)
        S.bufA[s0 + i][c0 + j] = fmaxf(acc[i][j] - corr[j], 0.f);
    __syncthreads();

    // G4
    {
      float4 bv4 = *(const float4*)(b2w + c0);
#pragma unroll
      for (int i = 0; i < 2; ++i) { acc[i][0] = bv4.x; acc[i][1] = bv4.y; acc[i][2] = bv4.z; acc[i][3] = bv4.w; }
    }
    gemm_tile2<128>(S.bufA[s0], S.bufA[s0 + 1], W2w + c0, acc);
    {
      float part[4] = {0.f, 0.f, 0.f, 0.f};
#pragma unroll
      for (int i = 0; i < 2; ++i)
#pragma unroll
        for (int j = 0; j < 4; ++j) {
          float al = 1.0f / (1.0f + __expf(-acc[i][j]));
          part[j] += al * S.fp[s0 + i][c0 + j];
        }
      __syncthreads();  // fin dead -> reuse as 16xHID reduction buffer
      float* redp = &S.fin[0][0];
      redp[(t >> 5) * HID + c0 + 0] = part[0];
      redp[(t >> 5) * HID + c0 + 1] = part[1];
      redp[(t >> 5) * HID + c0 + 2] = part[2];
      redp[(t >> 5) * HID + c0 + 3] = part[3];
    }
    __syncthreads();
    if (t < HID) {
      float* redp = &S.fin[0][0];
      float s = 0.f;
#pragma unroll
      for (int w = 0; w < 16; ++w) s += redp[w * HID + t];
      fout[(size_t)g * HID + t] = s;
    }
    __syncthreads();  // LDS fully consumed before next ticket
  }
}

// ---------------------------------------------------------------- fused
__global__ __launch_bounds__(512, 1) void sa_fused_kernel(
    const float* __restrict__ xyz, const float* __restrict__ feats,
    const float* __restrict__ W1f, const float* __restrict__ b1f,
    const float* __restrict__ W2f, const float* __restrict__ b2f,
    const float* __restrict__ W1w, const float* __restrict__ b1w,
    const float* __restrict__ W2w, const float* __restrict__ b2w,
    float* __restrict__ newxyz, float* __restrict__ fout, int* ctrl) {
  __shared__ SMemU sm;
  int* progress = ctrl;    // [0..7]
  int* ticket = ctrl + 8;  // [8]
  if (blockIdx.x < NB) {
    run_fps(xyz, newxyz, progress, blockIdx.x, sm.p);
    return;  // producer CU contributes only to the (short) tail anyway
  }
  run_consumer(xyz, feats, W1f, b1f, W2f, b2f, W1w, b1w, W2w, b2w, newxyz,
               fout, progress, ticket, sm.c);
}

extern "C" void kernel_launch(void* const* d_in, const int* in_sizes, int n_in,
                              void* d_out, int out_size, void* d_ws, size_t ws_size,
                              hipStream_t stream) {
  const float* xyz = (const float*)d_in[0];
  const float* feats = (const float*)d_in[1];
  const float* W1f = (const float*)d_in[2];
  const float* b1f = (const float*)d_in[3];
  const float* W2f = (const float*)d_in[4];
  const float* b2f = (const float*)d_in[5];
  const float* W1w = (const float*)d_in[6];
  const float* b1w = (const float*)d_in[7];
  const float* W2w = (const float*)d_in[8];
  const float* b2w = (const float*)d_in[9];

  float* newxyz = (float*)d_out;                          // (8,1024,3)
  float* fout = (float*)d_out + (size_t)NB * NPOINT * 3;  // (8,1024,128)
  int* ctrl = (int*)d_ws;  // progress[8] + ticket[1]

  hipMemsetAsync(ctrl, 0, 64, stream);
  // 256 blocks x 512 thr, 84KB LDS -> exactly 1 block/CU: producers get
  // dedicated CUs (R5 lesson), consumers get 8 waves for latency hiding
  // (R4 lesson: 4 waves starved the L2 weight stream at 8 q/us).
  sa_fused_kernel<<<256, 512, 0, stream>>>(xyz, feats, W1f, b1f, W2f, b2f,
                                           W1w, b1w, W2w, b2w, newxyz, fout,
                                           ctrl);
}

// Round 7
// 2428.728 us; speedup vs baseline: 1.0040x; 1.0040x over previous
//
#include <hip/hip_runtime.h>
#include <stdint.h>

#define NB 8
#define NPTS 4096
#define NPOINT 1024
#define NSAMPLE 32
#define FCH 64
#define HID 128
#define CAPW 160  // per-wave candidate capacity (expected ~15/segment)

typedef unsigned long long ull;

// d2 computed with EXACT numpy rounding/order: ((dx*dx + dy*dy) + dz*dz),
// no FMA contraction (FPS argmax + radius selection must match ref bitwise).
__device__ __forceinline__ float d2_exact(float ax, float ay, float az,
                                          float bx, float by, float bz) {
  float dx = ax - bx, dy = ay - by, dz = az - bz;
  return __fadd_rn(__fadd_rn(__fmul_rn(dx, dx), __fmul_rn(dy, dy)),
                   __fmul_rn(dz, dz));
}

// DPP f32 max step (identity 0 valid: dists >= 0). VALU pipe.
#define DPPMAX(v, ctrl)                                                     \
  v = fmaxf(v, __int_as_float(__builtin_amdgcn_update_dpp(                  \
                 0, __float_as_int(v), ctrl, 0xf, 0xf, true)))

// ---------------- shared-memory union (R4 layout, padded to 84KB) ----------
// 84KB pad guarantees 1 block/CU regardless of dispatcher quirks: producers
// keep dedicated CUs (R5 lesson), consumers keep R4's proven 4x4 tiling
// (R6 lesson: halving the tile doubles per-wave W traffic + overhead).
struct ProdS {
  float4 pts[NPTS];     // 64 KB
  float chunk[64 * 3];  // 64-centroid publish buffer
  float4 wkd4[2];       // per-wave max dist (parity dbuf)
  int4 wki4[2];         // per-wave argmax idx
};
struct ConsS {
  float fin[32][68];     // dxyz 0..2, feats 3..66, pad 67
  float bufA[32][HID];   // h1 then h2
  float fp[32][HID];     // f_prime
  float fm[HID];
  ull candseg[4][CAPW];  // per-wave radius candidates
  ull cand2[4 * CAPW];   // compacted
  int sidx[NSAMPLE];
  int scnt[4];
  int tkS;
};
union SMemU {
  ProdS p;
  ConsS c;
  unsigned char pad_[86016];  // 84KB -> 1 block/CU guaranteed
};

// ---------------------------------------------------------------- FPS
// R3/R4-proven chain. Publishes centroids in 64-chunks (flush stores by
// waves 0-2 + threadfence, barrier, release-store of progress[b]).
__device__ void run_fps(const float* __restrict__ xyz,
                        float* __restrict__ newxyz, int* progress, int b,
                        ProdS& S) {
  const int t = threadIdx.x;
  const int wid = t >> 6;
  const float* src = xyz + (size_t)b * NPTS * 3;
  float* dstb = newxyz + (size_t)b * NPOINT * 3;
  for (int j = t; j < NPTS; j += 256) {
    const float* p = src + 3 * j;
    S.pts[j] = make_float4(p[0], p[1], p[2], 0.f);
  }
  __syncthreads();
  const int base = t * 16;
  float px[16], py[16], pz[16], dist[16];
  const float4 c0 = S.pts[0];
  float bv = -INFINITY;
  int br = 0;
#pragma unroll
  for (int r = 0; r < 16; ++r) {
    float4 p = S.pts[base + r];
    px[r] = p.x; py[r] = p.y; pz[r] = p.z;
    dist[r] = d2_exact(px[r], py[r], pz[r], c0.x, c0.y, c0.z);
    bool c = dist[r] > bv;  // strict > keeps lowest r (idx) on ties
    bv = c ? dist[r] : bv;
    br = c ? r : br;
  }
  if (t == 0) {
    S.chunk[0] = c0.x; S.chunk[1] = c0.y; S.chunk[2] = c0.z;
  }
  for (int it = 1; it < NPOINT; ++it) {
    float wm = bv;
    DPPMAX(wm, 0x111); DPPMAX(wm, 0x112); DPPMAX(wm, 0x114); DPPMAX(wm, 0x118);
    DPPMAX(wm, 0x142); DPPMAX(wm, 0x143);
    float gmaxw =
        __int_as_float(__builtin_amdgcn_readlane(__float_as_int(wm), 63));
    ull m = __ballot(bv == gmaxw);
    int lead = __ffsll((long long)m) - 1;  // lowest lane == lowest index
    int widx = __builtin_amdgcn_readlane(base + br, lead);
    const int par = it & 1;
    if ((t & 63) == 0) {
      ((float*)&S.wkd4[par])[wid] = gmaxw;
      ((int*)&S.wki4[par])[wid] = widx;
    }
    __syncthreads();  // parity double-buffer -> single barrier/iter
    if ((it & 63) == 0) {
      if (t < 192) {
        dstb[(it - 64) * 3 + t] = S.chunk[t];
        __threadfence();
      }
      __syncthreads();
      if (t == 0)
        __hip_atomic_store(&progress[b], it, __ATOMIC_RELEASE,
                           __HIP_MEMORY_SCOPE_AGENT);
    }
    float4 dd = S.wkd4[par];
    int4 ii = S.wki4[par];
    float d = dd.x; int fi = ii.x;
    bool c1 = (dd.y > d) || (dd.y == d && ii.y < fi);
    d = c1 ? dd.y : d; fi = c1 ? ii.y : fi;
    bool c2 = (dd.z > d) || (dd.z == d && ii.z < fi);
    d = c2 ? dd.z : d; fi = c2 ? ii.z : fi;
    bool c3 = (dd.w > d) || (dd.w == d && ii.w < fi);
    fi = c3 ? ii.w : fi;
    const float4 cp = S.pts[fi];
    if (t == 0) {
      int slot = (it & 63) * 3;
      S.chunk[slot + 0] = cp.x;
      S.chunk[slot + 1] = cp.y;
      S.chunk[slot + 2] = cp.z;
    }
    bv = -INFINITY;
    br = 0;
#pragma unroll
    for (int r = 0; r < 16; ++r) {
      float dnew = d2_exact(px[r], py[r], pz[r], cp.x, cp.y, cp.z);
      float nd = fminf(dist[r], dnew);
      dist[r] = nd;
      bool c = nd > bv;
      bv = c ? nd : bv;
      br = c ? r : br;
    }
  }
  __syncthreads();  // chunk holds centroids [960,1024)
  if (t < 192) {
    dstb[(NPOINT - 64) * 3 + t] = S.chunk[t];
    __threadfence();
  }
  __syncthreads();
  if (t == 0)
    __hip_atomic_store(&progress[b], NPOINT, __ATOMIC_RELEASE,
                       __HIP_MEMORY_SCOPE_AGENT);
}

// ---------------------------------------------------------------- MLP gemms
// K=128 GEMM with REGISTER SOFTWARE PIPELINE: W prefetched 2 iterations
// (8 k-rows) ahead, A 1 iteration ahead. R4/R6 diagnosis: with 1 wave/SIMD
// the un-pipelined W load (~200-400cyc L1/L2 hit) serializes against the
// 128-cyc FMA block -> consumers latency-bound at 34K cyc/query. Prefetch
// indices are clamped (branchless, wave-uniform) so all loads are valid.
__device__ __forceinline__ void gemm128_pf(const float* __restrict__ a0,
                                           const float* __restrict__ a1,
                                           const float* __restrict__ a2,
                                           const float* __restrict__ a3,
                                           const float* __restrict__ W,
                                           float acc[4][4]) {
  float4 w[4], v[4], A[4];
#pragma unroll
  for (int i = 0; i < 4; ++i) w[i] = *(const float4*)(W + (size_t)i * HID);
#pragma unroll
  for (int i = 0; i < 4; ++i)
    v[i] = *(const float4*)(W + (size_t)(4 + i) * HID);
  A[0] = *(const float4*)(a0);
  A[1] = *(const float4*)(a1);
  A[2] = *(const float4*)(a2);
  A[3] = *(const float4*)(a3);
#pragma unroll 2
  for (int kb = 0; kb < 128; kb += 4) {
    const int ka = (kb + 4 < 128) ? (kb + 4) : 124;   // clamped A prefetch
    const int kw = (kb + 8 < 128) ? (kb + 8) : 120;   // clamped W prefetch
    float4 nA0 = *(const float4*)(a0 + ka);
    float4 nA1 = *(const float4*)(a1 + ka);
    float4 nA2 = *(const float4*)(a2 + ka);
    float4 nA3 = *(const float4*)(a3 + ka);
    float4 nw[4];
#pragma unroll
    for (int i = 0; i < 4; ++i)
      nw[i] = *(const float4*)(W + (size_t)(kw + i) * HID);
#pragma unroll
    for (int kk = 0; kk < 4; ++kk) {
      float4 ww = w[kk];
      float e0 = (&A[0].x)[kk], e1 = (&A[1].x)[kk];
      float e2 = (&A[2].x)[kk], e3 = (&A[3].x)[kk];
      acc[0][0] += e0 * ww.x; acc[0][1] += e0 * ww.y; acc[0][2] += e0 * ww.z; acc[0][3] += e0 * ww.w;
      acc[1][0] += e1 * ww.x; acc[1][1] += e1 * ww.y; acc[1][2] += e1 * ww.z; acc[1][3] += e1 * ww.w;
      acc[2][0] += e2 * ww.x; acc[2][1] += e2 * ww.y; acc[2][2] += e2 * ww.z; acc[2][3] += e2 * ww.w;
      acc[3][0] += e3 * ww.x; acc[3][1] += e3 * ww.y; acc[3][2] += e3 * ww.z; acc[3][3] += e3 * ww.w;
    }
#pragma unroll
    for (int i = 0; i < 4; ++i) w[i] = v[i];
#pragma unroll
    for (int i = 0; i < 4; ++i) v[i] = nw[i];
    A[0] = nA0; A[1] = nA1; A[2] = nA2; A[3] = nA3;
  }
}

// pipelined K=128 variant that also accumulates corr[j] = sum_k fm[k]*W[k][j]
__device__ __forceinline__ void gemm128_corr_pf(const float* __restrict__ a0,
                                                const float* __restrict__ a1,
                                                const float* __restrict__ a2,
                                                const float* __restrict__ a3,
                                                const float* __restrict__ W,
                                                const float* __restrict__ fm,
                                                float acc[4][4],
                                                float corr[4]) {
  float4 w[4], v[4], A[4], FM;
#pragma unroll
  for (int i = 0; i < 4; ++i) w[i] = *(const float4*)(W + (size_t)i * HID);
#pragma unroll
  for (int i = 0; i < 4; ++i)
    v[i] = *(const float4*)(W + (size_t)(4 + i) * HID);
  A[0] = *(const float4*)(a0);
  A[1] = *(const float4*)(a1);
  A[2] = *(const float4*)(a2);
  A[3] = *(const float4*)(a3);
  FM = *(const float4*)(fm);
#pragma unroll 2
  for (int kb = 0; kb < 128; kb += 4) {
    const int ka = (kb + 4 < 128) ? (kb + 4) : 124;
    const int kw = (kb + 8 < 128) ? (kb + 8) : 120;
    float4 nA0 = *(const float4*)(a0 + ka);
    float4 nA1 = *(const float4*)(a1 + ka);
    float4 nA2 = *(const float4*)(a2 + ka);
    float4 nA3 = *(const float4*)(a3 + ka);
    float4 nFM = *(const float4*)(fm + ka);
    float4 nw[4];
#pragma unroll
    for (int i = 0; i < 4; ++i)
      nw[i] = *(const float4*)(W + (size_t)(kw + i) * HID);
#pragma unroll
    for (int kk = 0; kk < 4; ++kk) {
      float4 ww = w[kk];
      float e0 = (&A[0].x)[kk], e1 = (&A[1].x)[kk];
      float e2 = (&A[2].x)[kk], e3 = (&A[3].x)[kk];
      float cf = (&FM.x)[kk];
      acc[0][0] += e0 * ww.x; acc[0][1] += e0 * ww.y; acc[0][2] += e0 * ww.z; acc[0][3] += e0 * ww.w;
      acc[1][0] += e1 * ww.x; acc[1][1] += e1 * ww.y; acc[1][2] += e1 * ww.z; acc[1][3] += e1 * ww.w;
      acc[2][0] += e2 * ww.x; acc[2][1] += e2 * ww.y; acc[2][2] += e2 * ww.z; acc[2][3] += e2 * ww.w;
      acc[3][0] += e3 * ww.x; acc[3][1] += e3 * ww.y; acc[3][2] += e3 * ww.z; acc[3][3] += e3 * ww.w;
      corr[0] += cf * ww.x; corr[1] += cf * ww.y; corr[2] += cf * ww.z; corr[3] += cf * ww.w;
    }
#pragma unroll
    for (int i = 0; i < 4; ++i) w[i] = v[i];
#pragma unroll
    for (int i = 0; i < 4; ++i) v[i] = nw[i];
    A[0] = nA0; A[1] = nA1; A[2] = nA2; A[3] = nA3;
    FM = nFM;
  }
}

// K=67 GEMM (G1 only; small share of work) — R4's streaming version.
__device__ __forceinline__ void gemm67(const float* __restrict__ a0,
                                       const float* __restrict__ a1,
                                       const float* __restrict__ a2,
                                       const float* __restrict__ a3,
                                       const float* __restrict__ W,
                                       float acc[4][4]) {
  int k = 0;
  for (; k + 4 <= 67; k += 4) {
    float4 A0 = *(const float4*)(a0 + k);
    float4 A1 = *(const float4*)(a1 + k);
    float4 A2 = *(const float4*)(a2 + k);
    float4 A3 = *(const float4*)(a3 + k);
#pragma unroll
    for (int kk = 0; kk < 4; ++kk) {
      float4 w = *(const float4*)(W + (size_t)(k + kk) * HID);
      float e0 = (&A0.x)[kk], e1 = (&A1.x)[kk], e2 = (&A2.x)[kk], e3 = (&A3.x)[kk];
      acc[0][0] += e0 * w.x; acc[0][1] += e0 * w.y; acc[0][2] += e0 * w.z; acc[0][3] += e0 * w.w;
      acc[1][0] += e1 * w.x; acc[1][1] += e1 * w.y; acc[1][2] += e1 * w.z; acc[1][3] += e1 * w.w;
      acc[2][0] += e2 * w.x; acc[2][1] += e2 * w.y; acc[2][2] += e2 * w.z; acc[2][3] += e2 * w.w;
      acc[3][0] += e3 * w.x; acc[3][1] += e3 * w.y; acc[3][2] += e3 * w.z; acc[3][3] += e3 * w.w;
    }
  }
  for (; k < 67; ++k) {
    float4 w = *(const float4*)(W + (size_t)k * HID);
    float e0 = a0[k], e1 = a1[k], e2 = a2[k], e3 = a3[k];
    acc[0][0] += e0 * w.x; acc[0][1] += e0 * w.y; acc[0][2] += e0 * w.z; acc[0][3] += e0 * w.w;
    acc[1][0] += e1 * w.x; acc[1][1] += e1 * w.y; acc[1][2] += e1 * w.z; acc[1][3] += e1 * w.w;
    acc[2][0] += e2 * w.x; acc[2][1] += e2 * w.y; acc[2][2] += e2 * w.z; acc[2][3] += e2 * w.w;
    acc[3][0] += e3 * w.x; acc[3][1] += e3 * w.y; acc[3][2] += e3 * w.z; acc[3][3] += e3 * w.w;
  }
}

// ---------------------------------------------------------------- consumer
__device__ void run_consumer(const float* __restrict__ xyz,
                             const float* __restrict__ feats,
                             const float* __restrict__ W1f,
                             const float* __restrict__ b1f,
                             const float* __restrict__ W2f,
                             const float* __restrict__ b2f,
                             const float* __restrict__ W1w,
                             const float* __restrict__ b1w,
                             const float* __restrict__ W2w,
                             const float* __restrict__ b2w,
                             const float* __restrict__ newxyz,
                             float* __restrict__ fout, int* progress,
                             int* ticket, ConsS& S) {
  const int t = threadIdx.x;
  const int wv = t >> 6;
  const int lane = t & 63;
  const float r2 = 0.0225f;  // np float32(RADIUS**2)

  while (true) {
    if (t == 0) S.tkS = atomicAdd(ticket, 1);
    __syncthreads();
    const int tk = S.tkS;
    if (tk >= NB * NPOINT) return;
    const int it = tk >> 3;
    const int b = tk & 7;
    const int g = b * NPOINT + it;

    // wait until centroid `it` of batch b is published
    if (t == 0) {
      while (__hip_atomic_load(&progress[b], __ATOMIC_RELAXED,
                               __HIP_MEMORY_SCOPE_AGENT) <= it)
        __builtin_amdgcn_s_sleep(32);
    }
    __syncthreads();
    {  // every thread acquires (orders its own subsequent loads)
      int pv = __hip_atomic_load(&progress[b], __ATOMIC_ACQUIRE,
                                 __HIP_MEMORY_SCOPE_AGENT);
      while (pv <= it) {
        __builtin_amdgcn_s_sleep(8);
        pv = __hip_atomic_load(&progress[b], __ATOMIC_ACQUIRE,
                               __HIP_MEMORY_SCOPE_AGENT);
      }
    }
    const float cx = newxyz[g * 3 + 0];
    const float cy = newxyz[g * 3 + 1];
    const float cz = newxyz[g * 3 + 2];

    // ---- knn: 4-wave scan, per-wave compaction, rank-select 32 smallest
    const float* src = xyz + (size_t)b * NPTS * 3;
    int cnt = 0;
    const int jb = wv * 1024;
    for (int j0 = jb; j0 < jb + 1024; j0 += 64) {
      const int p = j0 + lane;
      const float* pp = src + p * 3;
      float d2 = d2_exact(pp[0], pp[1], pp[2], cx, cy, cz);
      bool inr = (d2 <= r2);
      ull mask = __ballot(inr);
      if (inr) {
        int pos = cnt + __popcll(mask & ((1ull << lane) - 1ull));
        if (pos < CAPW)
          S.candseg[wv][pos] = ((ull)__float_as_uint(d2) << 32) | (unsigned)p;
      }
      cnt += __popcll(mask);
    }
    if (lane == 0) S.scnt[wv] = cnt < CAPW ? cnt : CAPW;
    __syncthreads();
    const int n0 = S.scnt[0], n1 = S.scnt[1], n2 = S.scnt[2], n3 = S.scnt[3];
    const int C = n0 + n1 + n2 + n3;
    {
      int off = (wv > 0 ? n0 : 0) + (wv > 1 ? n1 : 0) + (wv > 2 ? n2 : 0);
      int myn = S.scnt[wv];
      for (int i = lane; i < myn; i += 64) S.cand2[off + i] = S.candseg[wv][i];
    }
    __syncthreads();
    for (int tt = t; tt < C; tt += 256) {
      ull key = S.cand2[tt];
      int rank = 0;
      for (int u = 0; u < C; ++u) rank += (S.cand2[u] < key) ? 1 : 0;
      if (rank < NSAMPLE) S.sidx[rank] = (int)(key & 0xffffffffu);
    }
    if (C < NSAMPLE && wv == 0) {  // boundary fill: lowest-index outside pts
      const float* pp = src + lane * 3;
      float d2 = d2_exact(pp[0], pp[1], pp[2], cx, cy, cz);
      bool outr = !(d2 <= r2);
      ull mask = __ballot(outr);
      if (outr) {
        int pos = __popcll(mask & ((1ull << lane) - 1ull));
        if (pos < NSAMPLE - C) S.sidx[C + pos] = lane;
      }
    }
    __syncthreads();

    // ---- mlp (R3/R4-proven structure, pipelined GEMMs)
    if (t < 32) {
      const float* pp = src + (size_t)S.sidx[t] * 3;
      S.fin[t][0] = pp[0] - cx;
      S.fin[t][1] = pp[1] - cy;
      S.fin[t][2] = pp[2] - cz;
      S.fin[t][67] = 0.f;
    }
    for (int e = t; e < 32 * FCH; e += 256) {
      int s = e >> 6;
      int c = e & 63;
      S.fin[s][3 + c] = feats[((size_t)b * NPTS + S.sidx[s]) * FCH + c];
    }
    __syncthreads();

    const int s0 = (t >> 5) * 4;
    const int c0 = (t & 31) * 4;
    float acc[4][4];

    // G1
    {
      float4 bv4 = *(const float4*)(b1f + c0);
#pragma unroll
      for (int i = 0; i < 4; ++i) { acc[i][0] = bv4.x; acc[i][1] = bv4.y; acc[i][2] = bv4.z; acc[i][3] = bv4.w; }
    }
    gemm67(S.fin[s0], S.fin[s0 + 1], S.fin[s0 + 2], S.fin[s0 + 3], W1f + c0,
           acc);
#pragma unroll
    for (int i = 0; i < 4; ++i)
#pragma unroll
      for (int j = 0; j < 4; ++j) S.bufA[s0 + i][c0 + j] = fmaxf(acc[i][j], 0.f);
    __syncthreads();

    // G2
    {
      float4 bv4 = *(const float4*)(b2f + c0);
#pragma unroll
      for (int i = 0; i < 4; ++i) { acc[i][0] = bv4.x; acc[i][1] = bv4.y; acc[i][2] = bv4.z; acc[i][3] = bv4.w; }
    }
    gemm128_pf(S.bufA[s0], S.bufA[s0 + 1], S.bufA[s0 + 2], S.bufA[s0 + 3],
               W2f + c0, acc);
#pragma unroll
    for (int i = 0; i < 4; ++i)
#pragma unroll
      for (int j = 0; j < 4; ++j) S.fp[s0 + i][c0 + j] = fmaxf(acc[i][j], 0.f);
    __syncthreads();

    if (t < HID) {
      float s = 0.f;
#pragma unroll 8
      for (int i = 0; i < 32; ++i) s += S.fp[i][t];
      S.fm[t] = s * (1.0f / 32.0f);
    }
    __syncthreads();

    // G3: relu( fp@W1w[3:] + (b1w + dxyz@W1w[0:3]) - fm@W1w[3:] )
    float corr[4] = {0.f, 0.f, 0.f, 0.f};
    {
      float4 bv4 = *(const float4*)(b1w + c0);
      float4 w0 = *(const float4*)(W1w + 0 * HID + c0);
      float4 w1 = *(const float4*)(W1w + 1 * HID + c0);
      float4 w2 = *(const float4*)(W1w + 2 * HID + c0);
#pragma unroll
      for (int i = 0; i < 4; ++i) {
        float dx = S.fin[s0 + i][0], dy = S.fin[s0 + i][1], dz = S.fin[s0 + i][2];
        acc[i][0] = bv4.x + dx * w0.x + dy * w1.x + dz * w2.x;
        acc[i][1] = bv4.y + dx * w0.y + dy * w1.y + dz * w2.y;
        acc[i][2] = bv4.z + dx * w0.z + dy * w1.z + dz * w2.z;
        acc[i][3] = bv4.w + dx * w0.w + dy * w1.w + dz * w2.w;
      }
    }
    gemm128_corr_pf(S.fp[s0], S.fp[s0 + 1], S.fp[s0 + 2], S.fp[s0 + 3],
                    W1w + 3 * HID + c0, S.fm, acc, corr);
    __syncthreads();
#pragma unroll
    for (int i = 0; i < 4; ++i)
#pragma unroll
      for (int j = 0; j < 4; ++j)
        S.bufA[s0 + i][c0 + j] = fmaxf(acc[i][j] - corr[j], 0.f);
    __syncthreads();

    // G4
    {
      float4 bv4 = *(const float4*)(b2w + c0);
#pragma unroll
      for (int i = 0; i < 4; ++i) { acc[i][0] = bv4.x; acc[i][1] = bv4.y; acc[i][2] = bv4.z; acc[i][3] = bv4.w; }
    }
    gemm128_pf(S.bufA[s0], S.bufA[s0 + 1], S.bufA[s0 + 2], S.bufA[s0 + 3],
               W2w + c0, acc);
    {
      float part[4] = {0.f, 0.f, 0.f, 0.f};
#pragma unroll
      for (int i = 0; i < 4; ++i)
#pragma unroll
        for (int j = 0; j < 4; ++j) {
          float al = 1.0f / (1.0f + __expf(-acc[i][j]));
          part[j] += al * S.fp[s0 + i][c0 + j];
        }
      __syncthreads();  // fin dead -> reuse as 8xHID reduction buffer
      float* redp = &S.fin[0][0];
      redp[(t >> 5) * HID + c0 + 0] = part[0];
      redp[(t >> 5) * HID + c0 + 1] = part[1];
      redp[(t >> 5) * HID + c0 + 2] = part[2];
      redp[(t >> 5) * HID + c0 + 3] = part[3];
    }
    __syncthreads();
    if (t < HID) {
      float* redp = &S.fin[0][0];
      float s = 0.f;
#pragma unroll
      for (int w = 0; w < 8; ++w) s += redp[w * HID + t];
      fout[(size_t)g * HID + t] = s;
    }
    __syncthreads();  // LDS fully consumed before next ticket
  }
}

// ---------------------------------------------------------------- fused
__global__ __launch_bounds__(256, 1) void sa_fused_kernel(
    const float* __restrict__ xyz, const float* __restrict__ feats,
    const float* __restrict__ W1f, const float* __restrict__ b1f,
    const float* __restrict__ W2f, const float* __restrict__ b2f,
    const float* __restrict__ W1w, const float* __restrict__ b1w,
    const float* __restrict__ W2w, const float* __restrict__ b2w,
    float* __restrict__ newxyz, float* __restrict__ fout, int* ctrl) {
  __shared__ SMemU sm;
  int* progress = ctrl;    // [0..7]
  int* ticket = ctrl + 8;  // [8]
  if (blockIdx.x < NB) {
    run_fps(xyz, newxyz, progress, blockIdx.x, sm.p);
    __syncthreads();  // producer joins consumer pool for the tail
  }
  run_consumer(xyz, feats, W1f, b1f, W2f, b2f, W1w, b1w, W2w, b2w, newxyz,
               fout, progress, ticket, sm.c);
}

extern "C" void kernel_launch(void* const* d_in, const int* in_sizes, int n_in,
                              void* d_out, int out_size, void* d_ws, size_t ws_size,
                              hipStream_t stream) {
  const float* xyz = (const float*)d_in[0];
  const float* feats = (const float*)d_in[1];
  const float* W1f = (const float*)d_in[2];
  const float* b1f = (const float*)d_in[3];
  const float* W2f = (const float*)d_in[4];
  const float* b2f = (const float*)d_in[5];
  const float* W1w = (const float*)d_in[6];
  const float* b1w = (const float*)d_in[7];
  const float* W2w = (const float*)d_in[8];
  const float* b2w = (const float*)d_in[9];

  float* newxyz = (float*)d_out;                          // (8,1024,3)
  float* fout = (float*)d_out + (size_t)NB * NPOINT * 3;  // (8,1024,128)
  int* ctrl = (int*)d_ws;  // progress[8] + ticket[1]

  hipMemsetAsync(ctrl, 0, 64, stream);
  // 256 blocks x 256 thr, 84KB LDS -> exactly 1 block/CU (R4 topology:
  // producers on dedicated CUs). Consumer GEMMs now software-pipelined in
  // registers to hide the W-load latency that capped R4 at 8 q/us.
  sa_fused_kernel<<<256, 256, 0, stream>>>(xyz, feats, W1f, b1f, W2f, b2f,
                                           W1w, b1w, W2w, b2w, newxyz, fout,
                                           ctrl);
}

// Round 8
// 1262.384 us; speedup vs baseline: 1.9316x; 1.9239x over previous
//
#include <hip/hip_runtime.h>
#include <stdint.h>

#define NB 8
#define NPTS 4096
#define NPOINT 1024
#define NSAMPLE 32
#define FCH 64
#define HID 128
#define CAPW 160   // per-wave candidate capacity (expected ~15/segment)
#define LDW 132    // padded row: 4-row ds_read_b128 -> free 2-way conflict

typedef unsigned long long ull;

// d2 computed with EXACT numpy rounding/order: ((dx*dx + dy*dy) + dz*dz),
// no FMA contraction (FPS argmax + radius selection must match ref bitwise).
__device__ __forceinline__ float d2_exact(float ax, float ay, float az,
                                          float bx, float by, float bz) {
  float dx = ax - bx, dy = ay - by, dz = az - bz;
  return __fadd_rn(__fadd_rn(__fmul_rn(dx, dx), __fmul_rn(dy, dy)),
                   __fmul_rn(dz, dz));
}

// DPP f32 max step (identity 0 valid: dists >= 0). VALU pipe.
#define DPPMAX(v, ctrl)                                                     \
  v = fmaxf(v, __int_as_float(__builtin_amdgcn_update_dpp(                  \
                 0, __float_as_int(v), ctrl, 0xf, 0xf, true)))

// ---------------- shared-memory union --------------------------------------
// Consumer processes NQ=2 queries per pass (64-sample GEMMs): W re-read per
// query HALVES (R7 diagnosis: consumers are bound by redundant W reads
// through L1 + LDS instruction count, both O(1/channel-tile-width)).
struct ProdS {
  float4 pts[NPTS];     // 64 KB
  float chunk[64 * 3];  // 64-centroid publish buffer
  float4 wkd4[2];       // per-wave max dist (parity dbuf)
  int4 wki4[2];         // per-wave argmax idx
};
struct ConsS {
  float fin[64][68];  // per sample: dxyz 0..2, feats 3..66, pad 67 (17.4KB)
  float fm[2][HID];   // per-query mean
  int sidx[64];       // 2 queries x 32 samples
  int scnt[4];
  int tkS;
  union {  // knn candidates overlaid on GEMM buffers (dead during knn)
    float bufA[64][LDW];  // h1 then h2 (33.8KB)
    ull candseg[4][CAPW];
  };
  union {
    float fp[64][LDW];  // f_prime (33.8KB)
    ull cand2[4 * CAPW];
  };
};
union SMemU {
  ProdS p;
  ConsS c;
  unsigned char pad_[90112];  // 88KB -> 1 block/CU
};

// ---------------------------------------------------------------- FPS
// R3/R4-proven chain. Publishes centroids in 64-chunks (flush stores by
// waves 0-2 + threadfence, barrier, release-store of progress[b]).
__device__ void run_fps(const float* __restrict__ xyz,
                        float* __restrict__ newxyz, int* progress, int b,
                        ProdS& S) {
  const int t = threadIdx.x;
  const int wid = t >> 6;
  const float* src = xyz + (size_t)b * NPTS * 3;
  float* dstb = newxyz + (size_t)b * NPOINT * 3;
  for (int j = t; j < NPTS; j += 256) {
    const float* p = src + 3 * j;
    S.pts[j] = make_float4(p[0], p[1], p[2], 0.f);
  }
  __syncthreads();
  const int base = t * 16;
  float px[16], py[16], pz[16], dist[16];
  const float4 c0 = S.pts[0];
  float bv = -INFINITY;
  int br = 0;
#pragma unroll
  for (int r = 0; r < 16; ++r) {
    float4 p = S.pts[base + r];
    px[r] = p.x; py[r] = p.y; pz[r] = p.z;
    dist[r] = d2_exact(px[r], py[r], pz[r], c0.x, c0.y, c0.z);
    bool c = dist[r] > bv;  // strict > keeps lowest r (idx) on ties
    bv = c ? dist[r] : bv;
    br = c ? r : br;
  }
  if (t == 0) {
    S.chunk[0] = c0.x; S.chunk[1] = c0.y; S.chunk[2] = c0.z;
  }
  for (int it = 1; it < NPOINT; ++it) {
    float wm = bv;
    DPPMAX(wm, 0x111); DPPMAX(wm, 0x112); DPPMAX(wm, 0x114); DPPMAX(wm, 0x118);
    DPPMAX(wm, 0x142); DPPMAX(wm, 0x143);
    float gmaxw =
        __int_as_float(__builtin_amdgcn_readlane(__float_as_int(wm), 63));
    ull m = __ballot(bv == gmaxw);
    int lead = __ffsll((long long)m) - 1;  // lowest lane == lowest index
    int widx = __builtin_amdgcn_readlane(base + br, lead);
    const int par = it & 1;
    if ((t & 63) == 0) {
      ((float*)&S.wkd4[par])[wid] = gmaxw;
      ((int*)&S.wki4[par])[wid] = widx;
    }
    __syncthreads();  // parity double-buffer -> single barrier/iter
    if ((it & 63) == 0) {
      if (t < 192) {
        dstb[(it - 64) * 3 + t] = S.chunk[t];
        __threadfence();
      }
      __syncthreads();
      if (t == 0)
        __hip_atomic_store(&progress[b], it, __ATOMIC_RELEASE,
                           __HIP_MEMORY_SCOPE_AGENT);
    }
    float4 dd = S.wkd4[par];
    int4 ii = S.wki4[par];
    float d = dd.x; int fi = ii.x;
    bool c1 = (dd.y > d) || (dd.y == d && ii.y < fi);
    d = c1 ? dd.y : d; fi = c1 ? ii.y : fi;
    bool c2 = (dd.z > d) || (dd.z == d && ii.z < fi);
    d = c2 ? dd.z : d; fi = c2 ? ii.z : fi;
    bool c3 = (dd.w > d) || (dd.w == d && ii.w < fi);
    fi = c3 ? ii.w : fi;
    const float4 cp = S.pts[fi];
    if (t == 0) {
      int slot = (it & 63) * 3;
      S.chunk[slot + 0] = cp.x;
      S.chunk[slot + 1] = cp.y;
      S.chunk[slot + 2] = cp.z;
    }
    bv = -INFINITY;
    br = 0;
#pragma unroll
    for (int r = 0; r < 16; ++r) {
      float dnew = d2_exact(px[r], py[r], pz[r], cp.x, cp.y, cp.z);
      float nd = fminf(dist[r], dnew);
      dist[r] = nd;
      bool c = nd > bv;
      bv = c ? nd : bv;
      br = c ? r : br;
    }
  }
  __syncthreads();  // chunk holds centroids [960,1024)
  if (t < 192) {
    dstb[(NPOINT - 64) * 3 + t] = S.chunk[t];
    __threadfence();
  }
  __syncthreads();
  if (t == 0)
    __hip_atomic_store(&progress[b], NPOINT, __ATOMIC_RELEASE,
                       __HIP_MEMORY_SCOPE_AGENT);
}

// ---------------------------------------------------------------- MLP gemms
// 4-sample x 8-channel tile, plain template loops (R7 lesson: the compiler
// pipelines these better than manual register rotation). W streamed from
// global/L2 (R2 lesson: no LDS staging).
template <int K, int LD>
__device__ __forceinline__ void gemm48(const float* __restrict__ a0,
                                       const float* __restrict__ a1,
                                       const float* __restrict__ a2,
                                       const float* __restrict__ a3,
                                       const float* __restrict__ W,
                                       float acc[4][8]) {
  int k = 0;
  for (; k + 4 <= K; k += 4) {
    float4 A0 = *(const float4*)(a0 + k);
    float4 A1 = *(const float4*)(a1 + k);
    float4 A2 = *(const float4*)(a2 + k);
    float4 A3 = *(const float4*)(a3 + k);
#pragma unroll
    for (int kk = 0; kk < 4; ++kk) {
      float4 wlo = *(const float4*)(W + (size_t)(k + kk) * HID);
      float4 whi = *(const float4*)(W + (size_t)(k + kk) * HID + 4);
      float e0 = (&A0.x)[kk], e1 = (&A1.x)[kk], e2 = (&A2.x)[kk], e3 = (&A3.x)[kk];
#pragma unroll
      for (int j = 0; j < 4; ++j) {
        float wj = (&wlo.x)[j];
        acc[0][j] += e0 * wj; acc[1][j] += e1 * wj;
        acc[2][j] += e2 * wj; acc[3][j] += e3 * wj;
      }
#pragma unroll
      for (int j = 0; j < 4; ++j) {
        float wj = (&whi.x)[j];
        acc[0][4 + j] += e0 * wj; acc[1][4 + j] += e1 * wj;
        acc[2][4 + j] += e2 * wj; acc[3][4 + j] += e3 * wj;
      }
    }
  }
  for (; k < K; ++k) {
    float4 wlo = *(const float4*)(W + (size_t)k * HID);
    float4 whi = *(const float4*)(W + (size_t)k * HID + 4);
    float e0 = a0[k], e1 = a1[k], e2 = a2[k], e3 = a3[k];
#pragma unroll
    for (int j = 0; j < 4; ++j) {
      float wj = (&wlo.x)[j];
      acc[0][j] += e0 * wj; acc[1][j] += e1 * wj;
      acc[2][j] += e2 * wj; acc[3][j] += e3 * wj;
    }
#pragma unroll
    for (int j = 0; j < 4; ++j) {
      float wj = (&whi.x)[j];
      acc[0][4 + j] += e0 * wj; acc[1][4 + j] += e1 * wj;
      acc[2][4 + j] += e2 * wj; acc[3][4 + j] += e3 * wj;
    }
  }
}

// K=128 variant also accumulating corr[j] = sum_k fm[k]*W[k][j]
__device__ __forceinline__ void gemm48_corr(const float* __restrict__ a0,
                                            const float* __restrict__ a1,
                                            const float* __restrict__ a2,
                                            const float* __restrict__ a3,
                                            const float* __restrict__ W,
                                            const float* __restrict__ fm,
                                            float acc[4][8], float corr[8]) {
  for (int k = 0; k < HID; k += 4) {
    float4 A0 = *(const float4*)(a0 + k);
    float4 A1 = *(const float4*)(a1 + k);
    float4 A2 = *(const float4*)(a2 + k);
    float4 A3 = *(const float4*)(a3 + k);
    float4 FM = *(const float4*)(fm + k);
#pragma unroll
    for (int kk = 0; kk < 4; ++kk) {
      float4 wlo = *(const float4*)(W + (size_t)(k + kk) * HID);
      float4 whi = *(const float4*)(W + (size_t)(k + kk) * HID + 4);
      float e0 = (&A0.x)[kk], e1 = (&A1.x)[kk], e2 = (&A2.x)[kk], e3 = (&A3.x)[kk];
      float cf = (&FM.x)[kk];
#pragma unroll
      for (int j = 0; j < 4; ++j) {
        float wj = (&wlo.x)[j];
        acc[0][j] += e0 * wj; acc[1][j] += e1 * wj;
        acc[2][j] += e2 * wj; acc[3][j] += e3 * wj;
        corr[j] += cf * wj;
      }
#pragma unroll
      for (int j = 0; j < 4; ++j) {
        float wj = (&whi.x)[j];
        acc[0][4 + j] += e0 * wj; acc[1][4 + j] += e1 * wj;
        acc[2][4 + j] += e2 * wj; acc[3][4 + j] += e3 * wj;
        corr[4 + j] += cf * wj;
      }
    }
  }
}

// ---------------------------------------------------------------- consumer
__device__ void run_consumer(const float* __restrict__ xyz,
                             const float* __restrict__ feats,
                             const float* __restrict__ W1f,
                             const float* __restrict__ b1f,
                             const float* __restrict__ W2f,
                             const float* __restrict__ b2f,
                             const float* __restrict__ W1w,
                             const float* __restrict__ b1w,
                             const float* __restrict__ W2w,
                             const float* __restrict__ b2w,
                             const float* __restrict__ newxyz,
                             float* __restrict__ fout, int* progress,
                             int* ticket, ConsS& S) {
  const int t = threadIdx.x;
  const int wv = t >> 6;
  const int lane = t & 63;
  const float r2 = 0.0225f;  // np float32(RADIUS**2)

  while (true) {
    if (t == 0) S.tkS = atomicAdd(ticket, 1);
    __syncthreads();
    const int tk = S.tkS;
    if (tk >= NB * NPOINT / 2) return;
    const int i2 = tk >> 3;        // query-pair index 0..511
    const int b = tk & 7;
    const int it0 = 2 * i2;        // queries it0, it0+1
    const int g0 = b * NPOINT + it0;

    // wait until centroid it0+1 of batch b is published
    if (t == 0) {
      while (__hip_atomic_load(&progress[b], __ATOMIC_RELAXED,
                               __HIP_MEMORY_SCOPE_AGENT) <= it0 + 1)
        __builtin_amdgcn_s_sleep(32);
    }
    __syncthreads();
    {  // every thread acquires (orders its own subsequent loads)
      int pv = __hip_atomic_load(&progress[b], __ATOMIC_ACQUIRE,
                                 __HIP_MEMORY_SCOPE_AGENT);
      while (pv <= it0 + 1) {
        __builtin_amdgcn_s_sleep(8);
        pv = __hip_atomic_load(&progress[b], __ATOMIC_ACQUIRE,
                               __HIP_MEMORY_SCOPE_AGENT);
      }
    }
    const float* src = xyz + (size_t)b * NPTS * 3;

    // ---- knn x2 (sequential): 4-wave scan, compaction, rank-select 32
    for (int qq = 0; qq < 2; ++qq) {
      const int g = g0 + qq;
      const float cx = newxyz[g * 3 + 0];
      const float cy = newxyz[g * 3 + 1];
      const float cz = newxyz[g * 3 + 2];
      int cnt = 0;
      const int jb = wv * 1024;
      for (int j0 = jb; j0 < jb + 1024; j0 += 64) {
        const int p = j0 + lane;
        const float* pp = src + p * 3;
        float d2 = d2_exact(pp[0], pp[1], pp[2], cx, cy, cz);
        bool inr = (d2 <= r2);
        ull mask = __ballot(inr);
        if (inr) {
          int pos = cnt + __popcll(mask & ((1ull << lane) - 1ull));
          if (pos < CAPW)
            S.candseg[wv][pos] =
                ((ull)__float_as_uint(d2) << 32) | (unsigned)p;
        }
        cnt += __popcll(mask);
      }
      if (lane == 0) S.scnt[wv] = cnt < CAPW ? cnt : CAPW;
      __syncthreads();
      const int n0 = S.scnt[0], n1 = S.scnt[1], n2 = S.scnt[2], n3 = S.scnt[3];
      const int C = n0 + n1 + n2 + n3;
      {
        int off = (wv > 0 ? n0 : 0) + (wv > 1 ? n1 : 0) + (wv > 2 ? n2 : 0);
        int myn = S.scnt[wv];
        for (int i = lane; i < myn; i += 64)
          S.cand2[off + i] = S.candseg[wv][i];
      }
      __syncthreads();
      for (int tt = t; tt < C; tt += 256) {
        ull key = S.cand2[tt];
        int rank = 0;
        for (int u = 0; u < C; ++u) rank += (S.cand2[u] < key) ? 1 : 0;
        if (rank < NSAMPLE) S.sidx[qq * NSAMPLE + rank] = (int)(key & 0xffffffffu);
      }
      if (C < NSAMPLE && wv == 0) {  // boundary fill: lowest-idx outside pts
        const float* pp = src + lane * 3;
        float d2 = d2_exact(pp[0], pp[1], pp[2], cx, cy, cz);
        bool outr = !(d2 <= r2);
        ull mask = __ballot(outr);
        if (outr) {
          int pos = __popcll(mask & ((1ull << lane) - 1ull));
          if (pos < NSAMPLE - C) S.sidx[qq * NSAMPLE + C + pos] = lane;
        }
      }
      __syncthreads();
    }

    // ---- stage f_in for 64 samples (2 queries)
    if (t < 64) {
      const int g = g0 + (t >> 5);
      const float cx = newxyz[g * 3 + 0];
      const float cy = newxyz[g * 3 + 1];
      const float cz = newxyz[g * 3 + 2];
      const float* pp = src + (size_t)S.sidx[t] * 3;
      S.fin[t][0] = pp[0] - cx;
      S.fin[t][1] = pp[1] - cy;
      S.fin[t][2] = pp[2] - cz;
      S.fin[t][67] = 0.f;
    }
    for (int e = t; e < 64 * FCH; e += 256) {
      int s = e >> 6;
      int c = e & 63;
      S.fin[s][3 + c] = feats[((size_t)b * NPTS + S.sidx[s]) * FCH + c];
    }
    __syncthreads();

    const int sg = t >> 4;        // sample group 0..15
    const int s0 = sg * 4;
    const int c0 = (t & 15) * 8;  // 8-channel tile
    const int q = sg >> 3;        // this thread's query (0/1)
    float acc[4][8];

    // G1: relu(f_in @ W1f + b1f) -> bufA
    {
      float4 blo = *(const float4*)(b1f + c0);
      float4 bhi = *(const float4*)(b1f + c0 + 4);
#pragma unroll
      for (int i = 0; i < 4; ++i)
#pragma unroll
        for (int j = 0; j < 4; ++j) {
          acc[i][j] = (&blo.x)[j];
          acc[i][4 + j] = (&bhi.x)[j];
        }
    }
    gemm48<67, 68>(S.fin[s0], S.fin[s0 + 1], S.fin[s0 + 2], S.fin[s0 + 3],
                   W1f + c0, acc);
#pragma unroll
    for (int i = 0; i < 4; ++i)
#pragma unroll
      for (int j = 0; j < 8; ++j)
        S.bufA[s0 + i][c0 + j] = fmaxf(acc[i][j], 0.f);
    __syncthreads();

    // G2: relu(h1 @ W2f + b2f) -> fp
    {
      float4 blo = *(const float4*)(b2f + c0);
      float4 bhi = *(const float4*)(b2f + c0 + 4);
#pragma unroll
      for (int i = 0; i < 4; ++i)
#pragma unroll
        for (int j = 0; j < 4; ++j) {
          acc[i][j] = (&blo.x)[j];
          acc[i][4 + j] = (&bhi.x)[j];
        }
    }
    gemm48<128, LDW>(S.bufA[s0], S.bufA[s0 + 1], S.bufA[s0 + 2],
                     S.bufA[s0 + 3], W2f + c0, acc);
#pragma unroll
    for (int i = 0; i < 4; ++i)
#pragma unroll
      for (int j = 0; j < 8; ++j)
        S.fp[s0 + i][c0 + j] = fmaxf(acc[i][j], 0.f);
    __syncthreads();

    // per-query mean over samples
    {
      int qm = t >> 7;       // 0/1
      int ch = t & 127;
      float s = 0.f;
#pragma unroll 8
      for (int i = 0; i < 32; ++i) s += S.fp[qm * 32 + i][ch];
      S.fm[qm][ch] = s * (1.0f / 32.0f);
    }
    __syncthreads();

    // G3: relu( fp@W1w[3:] + (b1w + dxyz@W1w[0:3]) - fm@W1w[3:] ) -> bufA
    float corr[8] = {0.f, 0.f, 0.f, 0.f, 0.f, 0.f, 0.f, 0.f};
    {
      float4 blo = *(const float4*)(b1w + c0);
      float4 bhi = *(const float4*)(b1w + c0 + 4);
#pragma unroll
      for (int i = 0; i < 4; ++i) {
        float dx = S.fin[s0 + i][0], dy = S.fin[s0 + i][1],
              dz = S.fin[s0 + i][2];
#pragma unroll
        for (int h = 0; h < 2; ++h) {
          float4 w0 = *(const float4*)(W1w + 0 * HID + c0 + 4 * h);
          float4 w1 = *(const float4*)(W1w + 1 * HID + c0 + 4 * h);
          float4 w2 = *(const float4*)(W1w + 2 * HID + c0 + 4 * h);
          float4 bb = h ? bhi : blo;
#pragma unroll
          for (int j = 0; j < 4; ++j)
            acc[i][4 * h + j] = (&bb.x)[j] + dx * (&w0.x)[j] +
                                dy * (&w1.x)[j] + dz * (&w2.x)[j];
        }
      }
    }
    gemm48_corr(S.fp[s0], S.fp[s0 + 1], S.fp[s0 + 2], S.fp[s0 + 3],
                W1w + 3 * HID + c0, S.fm[q], acc, corr);
#pragma unroll
    for (int i = 0; i < 4; ++i)
#pragma unroll
      for (int j = 0; j < 8; ++j)
        S.bufA[s0 + i][c0 + j] = fmaxf(acc[i][j] - corr[j], 0.f);
    __syncthreads();

    // G4: alpha = sigmoid(h2 @ W2w + b2w); f_out = sum_s alpha*f'
    {
      float4 blo = *(const float4*)(b2w + c0);
      float4 bhi = *(const float4*)(b2w + c0 + 4);
#pragma unroll
      for (int i = 0; i < 4; ++i)
#pragma unroll
        for (int j = 0; j < 4; ++j) {
          acc[i][j] = (&blo.x)[j];
          acc[i][4 + j] = (&bhi.x)[j];
        }
    }
    gemm48<128, LDW>(S.bufA[s0], S.bufA[s0 + 1], S.bufA[s0 + 2],
                     S.bufA[s0 + 3], W2w + c0, acc);
    {
      float part[8] = {0.f, 0.f, 0.f, 0.f, 0.f, 0.f, 0.f, 0.f};
#pragma unroll
      for (int i = 0; i < 4; ++i)
#pragma unroll
        for (int j = 0; j < 8; ++j) {
          float al = 1.0f / (1.0f + __expf(-acc[i][j]));
          part[j] += al * S.fp[s0 + i][c0 + j];
        }
      __syncthreads();  // fin fully dead -> reuse as red[16][128]
      float* redp = &S.fin[0][0];
#pragma unroll
      for (int j = 0; j < 8; ++j) redp[sg * HID + c0 + j] = part[j];
    }
    __syncthreads();
    {
      int qm = t >> 7;  // 0/1
      int ch = t & 127;
      float* redp = &S.fin[0][0];
      float s = 0.f;
#pragma unroll
      for (int w = 0; w < 8; ++w) s += redp[(qm * 8 + w) * HID + ch];
      fout[(size_t)(g0 + qm) * HID + ch] = s;
    }
    __syncthreads();  // LDS fully consumed before next ticket
  }
}

// ---------------------------------------------------------------- fused
__global__ __launch_bounds__(256, 1) void sa_fused_kernel(
    const float* __restrict__ xyz, const float* __restrict__ feats,
    const float* __restrict__ W1f, const float* __restrict__ b1f,
    const float* __restrict__ W2f, const float* __restrict__ b2f,
    const float* __restrict__ W1w, const float* __restrict__ b1w,
    const float* __restrict__ W2w, const float* __restrict__ b2w,
    float* __restrict__ newxyz, float* __restrict__ fout, int* ctrl) {
  __shared__ SMemU sm;
  int* progress = ctrl;    // [0..7]
  int* ticket = ctrl + 8;  // [8]
  if (blockIdx.x < NB) {
    run_fps(xyz, newxyz, progress, blockIdx.x, sm.p);
    __syncthreads();  // producer joins consumer pool for the tail
  }
  run_consumer(xyz, feats, W1f, b1f, W2f, b2f, W1w, b1w, W2w, b2w, newxyz,
               fout, progress, ticket, sm.c);
}

extern "C" void kernel_launch(void* const* d_in, const int* in_sizes, int n_in,
                              void* d_out, int out_size, void* d_ws, size_t ws_size,
                              hipStream_t stream) {
  const float* xyz = (const float*)d_in[0];
  const float* feats = (const float*)d_in[1];
  const float* W1f = (const float*)d_in[2];
  const float* b1f = (const float*)d_in[3];
  const float* W2f = (const float*)d_in[4];
  const float* b2f = (const float*)d_in[5];
  const float* W1w = (const float*)d_in[6];
  const float* b1w = (const float*)d_in[7];
  const float* W2w = (const float*)d_in[8];
  const float* b2w = (const float*)d_in[9];

  float* newxyz = (float*)d_out;                          // (8,1024,3)
  float* fout = (float*)d_out + (size_t)NB * NPOINT * 3;  // (8,1024,128)
  int* ctrl = (int*)d_ws;  // progress[8] + ticket[1]

  hipMemsetAsync(ctrl, 0, 64, stream);
  // 256 blocks x 256 thr, 88KB LDS -> 1 block/CU: producers on dedicated
  // CUs. Consumers: NQ=2 queries/pass + 4x8 tiles halve both redundant
  // W reads (L1) and LDS instruction count per query.
  sa_fused_kernel<<<256, 256, 0, stream>>>(xyz, feats, W1f, b1f, W2f, b2f,
                                           W1w, b1w, W2w, b2w, newxyz, fout,
                                           ctrl);
}

// Round 9
// 1001.965 us; speedup vs baseline: 2.4337x; 1.2599x over previous
//
#include <hip/hip_runtime.h>
#include <stdint.h>

#define NB 8
#define NPTS 4096
#define NPOINT 1024
#define NSAMPLE 32
#define FCH 64
#define HID 128
#define CAPW 160  // per-wave candidate capacity (expected ~15/segment)

typedef unsigned long long ull;

// d2 computed with EXACT numpy rounding/order: ((dx*dx + dy*dy) + dz*dz),
// no FMA contraction (FPS argmax + radius selection must match ref bitwise).
__device__ __forceinline__ float d2_exact(float ax, float ay, float az,
                                          float bx, float by, float bz) {
  float dx = ax - bx, dy = ay - by, dz = az - bz;
  return __fadd_rn(__fadd_rn(__fmul_rn(dx, dx), __fmul_rn(dy, dy)),
                   __fmul_rn(dz, dz));
}

// DPP f32 max step (identity 0 valid: dists >= 0). VALU pipe.
#define DPPMAX(v, ctrl)                                                     \
  v = fmaxf(v, __int_as_float(__builtin_amdgcn_update_dpp(                  \
                 0, __float_as_int(v), ctrl, 0xf, 0xf, true)))

// ---------------- shared-memory union (R4 layout, NO pad: ~66.4KB) ---------
// 66.4KB -> 2 blocks/CU. Grid=512: block 256+i is block i's co-resident
// companion (XCD round-robin dispatch); companions of the 8 producers exit
// immediately, so producers stay SOLO (R5 lesson) while every consumer CU
// gets 8 waves (R4-R8 lesson: 4 waves/CU caps consumers at ~7.5 q/us;
// need ~13 to keep up with the FPS unlock rate).
struct ProdS {
  float4 pts[NPTS];     // 64 KB
  float chunk[64 * 3];  // 64-centroid publish buffer
  float4 wkd4[2];       // per-wave max dist (parity dbuf)
  int4 wki4[2];         // per-wave argmax idx
};
struct ConsS {
  float fin[32][68];     // dxyz 0..2, feats 3..66, pad 67
  float bufA[32][HID];   // h1 then h2
  float fp[32][HID];     // f_prime
  float fm[HID];
  ull candseg[4][CAPW];  // per-wave radius candidates
  ull cand2[4 * CAPW];   // compacted
  int sidx[NSAMPLE];
  int scnt[4];
  int tkS;
};
union SMemU {
  ProdS p;
  ConsS c;
};

// ---------------------------------------------------------------- FPS
// R3/R4-proven chain. Publishes centroids in 64-chunks (flush stores by
// waves 0-2 + threadfence, barrier, release-store of progress[b]).
__device__ void run_fps(const float* __restrict__ xyz,
                        float* __restrict__ newxyz, int* progress, int b,
                        ProdS& S) {
  const int t = threadIdx.x;
  const int wid = t >> 6;
  const float* src = xyz + (size_t)b * NPTS * 3;
  float* dstb = newxyz + (size_t)b * NPOINT * 3;
  for (int j = t; j < NPTS; j += 256) {
    const float* p = src + 3 * j;
    S.pts[j] = make_float4(p[0], p[1], p[2], 0.f);
  }
  __syncthreads();
  const int base = t * 16;
  float px[16], py[16], pz[16], dist[16];
  const float4 c0 = S.pts[0];
  float bv = -INFINITY;
  int br = 0;
#pragma unroll
  for (int r = 0; r < 16; ++r) {
    float4 p = S.pts[base + r];
    px[r] = p.x; py[r] = p.y; pz[r] = p.z;
    dist[r] = d2_exact(px[r], py[r], pz[r], c0.x, c0.y, c0.z);
    bool c = dist[r] > bv;  // strict > keeps lowest r (idx) on ties
    bv = c ? dist[r] : bv;
    br = c ? r : br;
  }
  if (t == 0) {
    S.chunk[0] = c0.x; S.chunk[1] = c0.y; S.chunk[2] = c0.z;
  }
  for (int it = 1; it < NPOINT; ++it) {
    float wm = bv;
    DPPMAX(wm, 0x111); DPPMAX(wm, 0x112); DPPMAX(wm, 0x114); DPPMAX(wm, 0x118);
    DPPMAX(wm, 0x142); DPPMAX(wm, 0x143);
    float gmaxw =
        __int_as_float(__builtin_amdgcn_readlane(__float_as_int(wm), 63));
    ull m = __ballot(bv == gmaxw);
    int lead = __ffsll((long long)m) - 1;  // lowest lane == lowest index
    int widx = __builtin_amdgcn_readlane(base + br, lead);
    const int par = it & 1;
    if ((t & 63) == 0) {
      ((float*)&S.wkd4[par])[wid] = gmaxw;
      ((int*)&S.wki4[par])[wid] = widx;
    }
    __syncthreads();  // parity double-buffer -> single barrier/iter
    if ((it & 63) == 0) {
      if (t < 192) {
        dstb[(it - 64) * 3 + t] = S.chunk[t];
        __threadfence();
      }
      __syncthreads();
      if (t == 0)
        __hip_atomic_store(&progress[b], it, __ATOMIC_RELEASE,
                           __HIP_MEMORY_SCOPE_AGENT);
    }
    float4 dd = S.wkd4[par];
    int4 ii = S.wki4[par];
    float d = dd.x; int fi = ii.x;
    bool c1 = (dd.y > d) || (dd.y == d && ii.y < fi);
    d = c1 ? dd.y : d; fi = c1 ? ii.y : fi;
    bool c2 = (dd.z > d) || (dd.z == d && ii.z < fi);
    d = c2 ? dd.z : d; fi = c2 ? ii.z : fi;
    bool c3 = (dd.w > d) || (dd.w == d && ii.w < fi);
    fi = c3 ? ii.w : fi;
    const float4 cp = S.pts[fi];
    if (t == 0) {
      int slot = (it & 63) * 3;
      S.chunk[slot + 0] = cp.x;
      S.chunk[slot + 1] = cp.y;
      S.chunk[slot + 2] = cp.z;
    }
    bv = -INFINITY;
    br = 0;
#pragma unroll
    for (int r = 0; r < 16; ++r) {
      float dnew = d2_exact(px[r], py[r], pz[r], cp.x, cp.y, cp.z);
      float nd = fminf(dist[r], dnew);
      dist[r] = nd;
      bool c = nd > bv;
      bv = c ? nd : bv;
      br = c ? r : br;
    }
  }
  __syncthreads();  // chunk holds centroids [960,1024)
  if (t < 192) {
    dstb[(NPOINT - 64) * 3 + t] = S.chunk[t];
    __threadfence();
  }
  __syncthreads();
  if (t == 0)
    __hip_atomic_store(&progress[b], NPOINT, __ATOMIC_RELEASE,
                       __HIP_MEMORY_SCOPE_AGENT);
}

// ---------------------------------------------------------------- MLP gemms
// R4's plain streamed-W loops (R7 lesson: compiler pipelines these better
// than manual register rotation; R2 lesson: no LDS staging of W).
template <int K>
__device__ __forceinline__ void gemm_tile(const float* __restrict__ a0,
                                          const float* __restrict__ a1,
                                          const float* __restrict__ a2,
                                          const float* __restrict__ a3,
                                          const float* __restrict__ W,
                                          float acc[4][4]) {
  int k = 0;
  for (; k + 4 <= K; k += 4) {
    float4 A0 = *(const float4*)(a0 + k);
    float4 A1 = *(const float4*)(a1 + k);
    float4 A2 = *(const float4*)(a2 + k);
    float4 A3 = *(const float4*)(a3 + k);
#pragma unroll
    for (int kk = 0; kk < 4; ++kk) {
      float4 w = *(const float4*)(W + (size_t)(k + kk) * HID);
      float e0 = (&A0.x)[kk], e1 = (&A1.x)[kk], e2 = (&A2.x)[kk], e3 = (&A3.x)[kk];
      acc[0][0] += e0 * w.x; acc[0][1] += e0 * w.y; acc[0][2] += e0 * w.z; acc[0][3] += e0 * w.w;
      acc[1][0] += e1 * w.x; acc[1][1] += e1 * w.y; acc[1][2] += e1 * w.z; acc[1][3] += e1 * w.w;
      acc[2][0] += e2 * w.x; acc[2][1] += e2 * w.y; acc[2][2] += e2 * w.z; acc[2][3] += e2 * w.w;
      acc[3][0] += e3 * w.x; acc[3][1] += e3 * w.y; acc[3][2] += e3 * w.z; acc[3][3] += e3 * w.w;
    }
  }
  for (; k < K; ++k) {
    float4 w = *(const float4*)(W + (size_t)k * HID);
    float e0 = a0[k], e1 = a1[k], e2 = a2[k], e3 = a3[k];
    acc[0][0] += e0 * w.x; acc[0][1] += e0 * w.y; acc[0][2] += e0 * w.z; acc[0][3] += e0 * w.w;
    acc[1][0] += e1 * w.x; acc[1][1] += e1 * w.y; acc[1][2] += e1 * w.z; acc[1][3] += e1 * w.w;
    acc[2][0] += e2 * w.x; acc[2][1] += e2 * w.y; acc[2][2] += e2 * w.z; acc[2][3] += e2 * w.w;
    acc[3][0] += e3 * w.x; acc[3][1] += e3 * w.y; acc[3][2] += e3 * w.z; acc[3][3] += e3 * w.w;
  }
}

__device__ __forceinline__ void gemm_tile_corr(const float* __restrict__ a0,
                                               const float* __restrict__ a1,
                                               const float* __restrict__ a2,
                                               const float* __restrict__ a3,
                                               const float* __restrict__ W,
                                               const float* __restrict__ fm,
                                               float acc[4][4], float corr[4]) {
  for (int k = 0; k < HID; k += 4) {
    float4 A0 = *(const float4*)(a0 + k);
    float4 A1 = *(const float4*)(a1 + k);
    float4 A2 = *(const float4*)(a2 + k);
    float4 A3 = *(const float4*)(a3 + k);
    float4 FM = *(const float4*)(fm + k);
#pragma unroll
    for (int kk = 0; kk < 4; ++kk) {
      float4 w = *(const float4*)(W + (size_t)(k + kk) * HID);
      float e0 = (&A0.x)[kk], e1 = (&A1.x)[kk], e2 = (&A2.x)[kk], e3 = (&A3.x)[kk];
      float cf = (&FM.x)[kk];
      acc[0][0] += e0 * w.x; acc[0][1] += e0 * w.y; acc[0][2] += e0 * w.z; acc[0][3] += e0 * w.w;
      acc[1][0] += e1 * w.x; acc[1][1] += e1 * w.y; acc[1][2] += e1 * w.z; acc[1][3] += e1 * w.w;
      acc[2][0] += e2 * w.x; acc[2][1] += e2 * w.y; acc[2][2] += e2 * w.z; acc[2][3] += e2 * w.w;
      acc[3][0] += e3 * w.x; acc[3][1] += e3 * w.y; acc[3][2] += e3 * w.z; acc[3][3] += e3 * w.w;
      corr[0] += cf * w.x; corr[1] += cf * w.y; corr[2] += cf * w.z; corr[3] += cf * w.w;
    }
  }
}

// ---------------------------------------------------------------- consumer
__device__ void run_consumer(const float* __restrict__ xyz,
                             const float* __restrict__ feats,
                             const float* __restrict__ W1f,
                             const float* __restrict__ b1f,
                             const float* __restrict__ W2f,
                             const float* __restrict__ b2f,
                             const float* __restrict__ W1w,
                             const float* __restrict__ b1w,
                             const float* __restrict__ W2w,
                             const float* __restrict__ b2w,
                             const float* __restrict__ newxyz,
                             float* __restrict__ fout, int* progress,
                             int* ticket, ConsS& S) {
  const int t = threadIdx.x;
  const int wv = t >> 6;
  const int lane = t & 63;
  const float r2 = 0.0225f;  // np float32(RADIUS**2)

  while (true) {
    if (t == 0) S.tkS = atomicAdd(ticket, 1);
    __syncthreads();
    const int tk = S.tkS;
    if (tk >= NB * NPOINT) return;
    const int it = tk >> 3;
    const int b = tk & 7;
    const int g = b * NPOINT + it;

    // wait until centroid `it` of batch b is published
    if (t == 0) {
      while (__hip_atomic_load(&progress[b], __ATOMIC_RELAXED,
                               __HIP_MEMORY_SCOPE_AGENT) <= it)
        __builtin_amdgcn_s_sleep(32);
    }
    __syncthreads();
    {  // every thread acquires (orders its own subsequent loads)
      int pv = __hip_atomic_load(&progress[b], __ATOMIC_ACQUIRE,
                                 __HIP_MEMORY_SCOPE_AGENT);
      while (pv <= it) {
        __builtin_amdgcn_s_sleep(8);
        pv = __hip_atomic_load(&progress[b], __ATOMIC_ACQUIRE,
                               __HIP_MEMORY_SCOPE_AGENT);
      }
    }
    const float cx = newxyz[g * 3 + 0];
    const float cy = newxyz[g * 3 + 1];
    const float cz = newxyz[g * 3 + 2];

    // ---- knn: 4-wave scan, per-wave compaction, rank-select 32 smallest
    const float* src = xyz + (size_t)b * NPTS * 3;
    int cnt = 0;
    const int jb = wv * 1024;
    for (int j0 = jb; j0 < jb + 1024; j0 += 64) {
      const int p = j0 + lane;
      const float* pp = src + p * 3;
      float d2 = d2_exact(pp[0], pp[1], pp[2], cx, cy, cz);
      bool inr = (d2 <= r2);
      ull mask = __ballot(inr);
      if (inr) {
        int pos = cnt + __popcll(mask & ((1ull << lane) - 1ull));
        if (pos < CAPW)
          S.candseg[wv][pos] = ((ull)__float_as_uint(d2) << 32) | (unsigned)p;
      }
      cnt += __popcll(mask);
    }
    if (lane == 0) S.scnt[wv] = cnt < CAPW ? cnt : CAPW;
    __syncthreads();
    const int n0 = S.scnt[0], n1 = S.scnt[1], n2 = S.scnt[2], n3 = S.scnt[3];
    const int C = n0 + n1 + n2 + n3;
    {
      int off = (wv > 0 ? n0 : 0) + (wv > 1 ? n1 : 0) + (wv > 2 ? n2 : 0);
      int myn = S.scnt[wv];
      for (int i = lane; i < myn; i += 64) S.cand2[off + i] = S.candseg[wv][i];
    }
    __syncthreads();
    for (int tt = t; tt < C; tt += 256) {
      ull key = S.cand2[tt];
      int rank = 0;
      for (int u = 0; u < C; ++u) rank += (S.cand2[u] < key) ? 1 : 0;
      if (rank < NSAMPLE) S.sidx[rank] = (int)(key & 0xffffffffu);
    }
    if (C < NSAMPLE && wv == 0) {  // boundary fill: lowest-index outside pts
      const float* pp = src + lane * 3;
      float d2 = d2_exact(pp[0], pp[1], pp[2], cx, cy, cz);
      bool outr = !(d2 <= r2);
      ull mask = __ballot(outr);
      if (outr) {
        int pos = __popcll(mask & ((1ull << lane) - 1ull));
        if (pos < NSAMPLE - C) S.sidx[C + pos] = lane;
      }
    }
    __syncthreads();

    // ---- mlp (R3/R4-proven structure)
    if (t < 32) {
      const float* pp = src + (size_t)S.sidx[t] * 3;
      S.fin[t][0] = pp[0] - cx;
      S.fin[t][1] = pp[1] - cy;
      S.fin[t][2] = pp[2] - cz;
      S.fin[t][67] = 0.f;
    }
    for (int e = t; e < 32 * FCH; e += 256) {
      int s = e >> 6;
      int c = e & 63;
      S.fin[s][3 + c] = feats[((size_t)b * NPTS + S.sidx[s]) * FCH + c];
    }
    __syncthreads();

    const int s0 = (t >> 5) * 4;
    const int c0 = (t & 31) * 4;
    float acc[4][4];

    // G1
    {
      float4 bv4 = *(const float4*)(b1f + c0);
#pragma unroll
      for (int i = 0; i < 4; ++i) { acc[i][0] = bv4.x; acc[i][1] = bv4.y; acc[i][2] = bv4.z; acc[i][3] = bv4.w; }
    }
    gemm_tile<67>(S.fin[s0], S.fin[s0 + 1], S.fin[s0 + 2], S.fin[s0 + 3],
                  W1f + c0, acc);
#pragma unroll
    for (int i = 0; i < 4; ++i)
#pragma unroll
      for (int j = 0; j < 4; ++j) S.bufA[s0 + i][c0 + j] = fmaxf(acc[i][j], 0.f);
    __syncthreads();

    // G2
    {
      float4 bv4 = *(const float4*)(b2f + c0);
#pragma unroll
      for (int i = 0; i < 4; ++i) { acc[i][0] = bv4.x; acc[i][1] = bv4.y; acc[i][2] = bv4.z; acc[i][3] = bv4.w; }
    }
    gemm_tile<128>(S.bufA[s0], S.bufA[s0 + 1], S.bufA[s0 + 2], S.bufA[s0 + 3],
                   W2f + c0, acc);
#pragma unroll
    for (int i = 0; i < 4; ++i)
#pragma unroll
      for (int j = 0; j < 4; ++j) S.fp[s0 + i][c0 + j] = fmaxf(acc[i][j], 0.f);
    __syncthreads();

    if (t < HID) {
      float s = 0.f;
#pragma unroll 8
      for (int i = 0; i < 32; ++i) s += S.fp[i][t];
      S.fm[t] = s * (1.0f / 32.0f);
    }
    __syncthreads();

    // G3: relu( fp@W1w[3:] + (b1w + dxyz@W1w[0:3]) - fm@W1w[3:] )
    float corr[4] = {0.f, 0.f, 0.f, 0.f};
    {
      float4 bv4 = *(const float4*)(b1w + c0);
      float4 w0 = *(const float4*)(W1w + 0 * HID + c0);
      float4 w1 = *(const float4*)(W1w + 1 * HID + c0);
      float4 w2 = *(const float4*)(W1w + 2 * HID + c0);
#pragma unroll
      for (int i = 0; i < 4; ++i) {
        float dx = S.fin[s0 + i][0], dy = S.fin[s0 + i][1], dz = S.fin[s0 + i][2];
        acc[i][0] = bv4.x + dx * w0.x + dy * w1.x + dz * w2.x;
        acc[i][1] = bv4.y + dx * w0.y + dy * w1.y + dz * w2.y;
        acc[i][2] = bv4.z + dx * w0.z + dy * w1.z + dz * w2.z;
        acc[i][3] = bv4.w + dx * w0.w + dy * w1.w + dz * w2.w;
      }
    }
    gemm_tile_corr(S.fp[s0], S.fp[s0 + 1], S.fp[s0 + 2], S.fp[s0 + 3],
                   W1w + 3 * HID + c0, S.fm, acc, corr);
    __syncthreads();
#pragma unroll
    for (int i = 0; i < 4; ++i)
#pragma unroll
      for (int j = 0; j < 4; ++j)
        S.bufA[s0 + i][c0 + j] = fmaxf(acc[i][j] - corr[j], 0.f);
    __syncthreads();

    // G4
    {
      float4 bv4 = *(const float4*)(b2w + c0);
#pragma unroll
      for (int i = 0; i < 4; ++i) { acc[i][0] = bv4.x; acc[i][1] = bv4.y; acc[i][2] = bv4.z; acc[i][3] = bv4.w; }
    }
    gemm_tile<128>(S.bufA[s0], S.bufA[s0 + 1], S.bufA[s0 + 2], S.bufA[s0 + 3],
                   W2w + c0, acc);
    {
      float part[4] = {0.f, 0.f, 0.f, 0.f};
#pragma unroll
      for (int i = 0; i < 4; ++i)
#pragma unroll
        for (int j = 0; j < 4; ++j) {
          float al = 1.0f / (1.0f + __expf(-acc[i][j]));
          part[j] += al * S.fp[s0 + i][c0 + j];
        }
      __syncthreads();  // fin dead -> reuse as 8xHID reduction buffer
      float* redp = &S.fin[0][0];
      redp[(t >> 5) * HID + c0 + 0] = part[0];
      redp[(t >> 5) * HID + c0 + 1] = part[1];
      redp[(t >> 5) * HID + c0 + 2] = part[2];
      redp[(t >> 5) * HID + c0 + 3] = part[3];
    }
    __syncthreads();
    if (t < HID) {
      float* redp = &S.fin[0][0];
      float s = 0.f;
#pragma unroll
      for (int w = 0; w < 8; ++w) s += redp[w * HID + t];
      fout[(size_t)g * HID + t] = s;
    }
    __syncthreads();  // LDS fully consumed before next ticket
  }
}

// ---------------------------------------------------------------- fused
__global__ __launch_bounds__(256, 2) void sa_fused_kernel(
    const float* __restrict__ xyz, const float* __restrict__ feats,
    const float* __restrict__ W1f, const float* __restrict__ b1f,
    const float* __restrict__ W2f, const float* __restrict__ b2f,
    const float* __restrict__ W1w, const float* __restrict__ b1w,
    const float* __restrict__ W2w, const float* __restrict__ b2w,
    float* __restrict__ newxyz, float* __restrict__ fout, int* ctrl) {
  __shared__ SMemU sm;
  int* progress = ctrl;    // [0..7]
  int* ticket = ctrl + 8;  // [8]
  if (blockIdx.x < NB) {
    run_fps(xyz, newxyz, progress, blockIdx.x, sm.p);
    __syncthreads();  // producer joins consumer pool for the tail
  } else if (blockIdx.x >= 256 && blockIdx.x < 256 + NB) {
    return;  // companion of a producer block (XCD round-robin): keep that
             // CU's second slot EMPTY so the FPS latency chain runs solo
  }
  run_consumer(xyz, feats, W1f, b1f, W2f, b2f, W1w, b1w, W2w, b2w, newxyz,
               fout, progress, ticket, sm.c);
}

extern "C" void kernel_launch(void* const* d_in, const int* in_sizes, int n_in,
                              void* d_out, int out_size, void* d_ws, size_t ws_size,
                              hipStream_t stream) {
  const float* xyz = (const float*)d_in[0];
  const float* feats = (const float*)d_in[1];
  const float* W1f = (const float*)d_in[2];
  const float* b1f = (const float*)d_in[3];
  const float* W2f = (const float*)d_in[4];
  const float* b2f = (const float*)d_in[5];
  const float* W1w = (const float*)d_in[6];
  const float* b1w = (const float*)d_in[7];
  const float* W2w = (const float*)d_in[8];
  const float* b2w = (const float*)d_in[9];

  float* newxyz = (float*)d_out;                          // (8,1024,3)
  float* fout = (float*)d_out + (size_t)NB * NPOINT * 3;  // (8,1024,128)
  int* ctrl = (int*)d_ws;  // progress[8] + ticket[1]

  hipMemsetAsync(ctrl, 0, 64, stream);
  // 512 blocks x 256 thr, 66.4KB LDS -> exactly 2 blocks/CU (512 = full
  // capacity -> all co-resident, no deadlock). Producers (0-7) solo on their
  // CUs via the companion-exit trick; every other CU runs 2 consumer blocks
  // = 8 waves, the TLP the W-load stream needs.
  sa_fused_kernel<<<512, 256, 0, stream>>>(xyz, feats, W1f, b1f, W2f, b2f,
                                           W1w, b1w, W2w, b2w, newxyz, fout,
                                           ctrl);
}